// Round 9
// baseline (1142.279 us; speedup 1.0000x reference)
//
#include <hip/hip_runtime.h>
#include <hip/hip_fp16.h>

#define NN 50000
#define NE 800000
#define HIDD 128
#define FEAT_E 16
#define NGRAPH 8

typedef __attribute__((ext_vector_type(2))) _Float16 half2_t;
typedef __attribute__((ext_vector_type(8))) _Float16 half8_t;
typedef __attribute__((ext_vector_type(4))) float floatx4;

// ---- order-preserving float<->uint encoding for atomicMax on floats ----
__device__ __forceinline__ unsigned int fenc(float f) {
  unsigned int u = __float_as_uint(f);
  return (u & 0x80000000u) ? ~u : (u | 0x80000000u);
}
__device__ __forceinline__ float fdec(unsigned int u) {
  if (u == 0u) return 0.0f;
  float f = (u & 0x80000000u) ? __uint_as_float(u & 0x7fffffffu)
                              : __uint_as_float(~u);
  return __builtin_isfinite(f) ? f : 0.0f;
}

__device__ __forceinline__ half8_t splat8(_Float16 v) {
  return (half8_t){v, v, v, v, v, v, v, v};
}
__device__ __forceinline__ half8_t hmax8(half8_t a, half8_t b) {
#if __has_builtin(__builtin_elementwise_max)
  return __builtin_elementwise_max(a, b);
#else
  half8_t r;
#pragma unroll
  for (int i = 0; i < 8; ++i) r[i] = a[i] > b[i] ? a[i] : b[i];
  return r;
#endif
}
__device__ __forceinline__ float dot_att(half8_t lk, half2_t t01, half2_t t23,
                                         half2_t t45, half2_t t67) {
#if __has_builtin(__builtin_amdgcn_fdot2)
  float p = __builtin_amdgcn_fdot2((half2_t){lk[0], lk[1]}, t01, 0.f, false);
  p = __builtin_amdgcn_fdot2((half2_t){lk[2], lk[3]}, t23, p, false);
  p = __builtin_amdgcn_fdot2((half2_t){lk[4], lk[5]}, t45, p, false);
  p = __builtin_amdgcn_fdot2((half2_t){lk[6], lk[7]}, t67, p, false);
  return p;
#else
  float p = 0.f;
  p += (float)lk[0] * (float)t01[0] + (float)lk[1] * (float)t01[1];
  p += (float)lk[2] * (float)t23[0] + (float)lk[3] * (float)t23[1];
  p += (float)lk[4] * (float)t45[0] + (float)lk[5] * (float)t45[1];
  p += (float)lk[6] * (float)t67[0] + (float)lk[7] * (float)t67[1];
  return p;
#endif
}

// ---- prep: wtg[which(2)][r(128)][col(128)] fp16, col = k ^ ((r&7)<<3).
// Row r holds W[:, (r&15)*8 + (r>>4)] -> identity output layout in the
// node_linear epilogue (lane arow stores channels [arow*8, arow*8+8)).
__global__ void prep_wt_k(const float* __restrict__ Wl, const float* __restrict__ Wr,
                          _Float16* __restrict__ wtg) {
  const int r = blockIdx.x & 127;
  const int which = blockIdx.x >> 7;
  const int k = threadIdx.x;  // 0..127
  const float* W = which ? Wr : Wl;
  const int oc_src = (r & 15) * 8 + (r >> 4);
  const int col = k ^ ((r & 7) << 3);
  wtg[(which * 128 + r) * 128 + col] = (_Float16)W[k * 128 + oc_src];
}

// ---- A-fragment loaders (fp32 input layer 1, fp16 layer 2) ----
__device__ __forceinline__ half8_t load_a8(const _Float16* p) {
  return *(const half8_t*)p;
}
__device__ __forceinline__ half8_t load_a8(const float* p) {
  const float4 f0 = *(const float4*)p;
  const float4 f1 = *(const float4*)(p + 4);
  return (half8_t){(_Float16)f0.x, (_Float16)f0.y, (_Float16)f0.z, (_Float16)f0.w,
                   (_Float16)f1.x, (_Float16)f1.y, (_Float16)f1.z, (_Float16)f1.w};
}

// ---- node linear via MFMA, LDS-staged swizzled weights (R8, verified) ----
template <typename TIN>
__global__ __launch_bounds__(256) void node_linear_mfma_k(
    const TIN* __restrict__ x, const _Float16* __restrict__ wtg,
    const float* __restrict__ bl, const float* __restrict__ br,
    _Float16* __restrict__ xl16, _Float16* __restrict__ xr16) {
  __shared__ _Float16 wt[128 * 128];  // 32 KB
  const int tid = threadIdx.x;
  const int which = blockIdx.y;
  const _Float16* wsrc = wtg + which * (128 * 128);
  const float* bias128 = which ? br : bl;
  _Float16* out = which ? xr16 : xl16;
  {
    const half8_t* src = (const half8_t*)wsrc;
    half8_t* dstl = (half8_t*)wt;
#pragma unroll
    for (int it = 0; it < 8; ++it)
      dstl[it * 256 + tid] = src[it * 256 + tid];
  }
  __syncthreads();

  const int wv = tid >> 6, lane = tid & 63;
  const int arow = lane & 15, kq = lane >> 4;
  const int nbase = blockIdx.x * 64 + wv * 16;
  int nload = nbase + arow;
  if (nload >= NN) nload = NN - 1;
  floatx4 acc[8];
#pragma unroll
  for (int t = 0; t < 8; ++t) acc[t] = (floatx4){0.f, 0.f, 0.f, 0.f};
#pragma unroll
  for (int kb = 0; kb < 4; ++kb) {
    const half8_t a = load_a8(x + (size_t)nload * 128 + kb * 32 + kq * 8);
    const int colbase = (kb * 32 + kq * 8) ^ ((arow & 7) << 3);
#pragma unroll
    for (int t = 0; t < 8; ++t) {
      const half8_t b = *(const half8_t*)&wt[(t * 16 + arow) * 128 + colbase];
      acc[t] = __builtin_amdgcn_mfma_f32_16x16x32_f16(a, b, acc[t], 0, 0, 0);
    }
  }
  const float4 bv0 = *(const float4*)&bias128[arow * 8];
  const float4 bv1 = *(const float4*)&bias128[arow * 8 + 4];
  const float bv[8] = {bv0.x, bv0.y, bv0.z, bv0.w, bv1.x, bv1.y, bv1.z, bv1.w};
#pragma unroll
  for (int i = 0; i < 4; ++i) {
    const int n = nbase + kq * 4 + i;
    if (n < NN) {
      half8_t v;
#pragma unroll
      for (int t = 0; t < 8; ++t) v[t] = (_Float16)(acc[t][i] + bv[t]);
      *(half8_t*)(out + (size_t)n * 128 + arow * 8) = v;
    }
  }
}

// ---- CSR build: count -> single-block scan -> place (dst-sorted edges) ----
__global__ void count_k(const int* __restrict__ dst, int* __restrict__ cnt) {
  const int e = blockIdx.x * blockDim.x + threadIdx.x;
  if (e >= NE) return;
  atomicAdd(&cnt[dst[e]], 1);
}

// one block, 1024 threads; thread t scans nodes [t*49, t*49+49)
__global__ __launch_bounds__(1024) void scan_k(const int* __restrict__ cnt,
                                               int* __restrict__ offs,
                                               int* __restrict__ cursor) {
  __shared__ int part[1024];
  const int t = threadIdx.x;
  const int base = t * 49;
  int s = 0;
  for (int i = 0; i < 49; ++i) {
    const int idx = base + i;
    if (idx < NN) s += cnt[idx];
  }
  part[t] = s;
  __syncthreads();
  for (int o = 1; o < 1024; o <<= 1) {   // Hillis-Steele inclusive scan
    const int v = (t >= o) ? part[t - o] : 0;
    __syncthreads();
    part[t] += v;
    __syncthreads();
  }
  int run = (t == 0) ? 0 : part[t - 1];  // exclusive prefix of this chunk
  for (int i = 0; i < 49; ++i) {
    const int idx = base + i;
    if (idx < NN) {
      offs[idx] = run;
      cursor[idx] = run;
      run += cnt[idx];
    }
  }
  if (t == 0) offs[NN] = NE;
}

__global__ void place_k(const int* __restrict__ src, const int* __restrict__ dst,
                        const float* __restrict__ eattr, int* __restrict__ cursor,
                        int* __restrict__ srcB, _Float16* __restrict__ eattB) {
  const int e = blockIdx.x * blockDim.x + threadIdx.x;
  if (e >= NE) return;
  const float4* ea = (const float4*)(eattr + (size_t)e * FEAT_E);
  const float4 a0 = ea[0], a1 = ea[1], a2 = ea[2], a3 = ea[3];
  const half8_t h0 = {(_Float16)a0.x, (_Float16)a0.y, (_Float16)a0.z, (_Float16)a0.w,
                      (_Float16)a1.x, (_Float16)a1.y, (_Float16)a1.z, (_Float16)a1.w};
  const half8_t h1 = {(_Float16)a2.x, (_Float16)a2.y, (_Float16)a2.z, (_Float16)a2.w,
                      (_Float16)a3.x, (_Float16)a3.y, (_Float16)a3.z, (_Float16)a3.w};
  const int pos = atomicAdd(&cursor[dst[e]], 1);
  srcB[pos] = src[e];
  half8_t* eo = (half8_t*)(eattB + (size_t)pos * FEAT_E);
  eo[0] = h0; eo[1] = h1;
}

// ---- FUSED per-node GATv2 (R8 body on dense CSR streams) ----
// block 256 = 4 waves, one wave per destination node (grid = NN/4).
// Wave: 4 edge-slots (slot = lane>>4) x 16 lanes; lane owns 8 contiguous
// channels. srcB/eattB now DESTINATION-SORTED: slot s handles rows
// o0+2s, o0+2s+1 (+8k) -> wave reads 256 B contiguous per iteration; the
// only remaining random stream is the xl row gather. Tail via per-edge
// mask (w=0). No max-shift: logits O(1); softmax shift-invariant
// (absmax 0.0 rounds 1-8).
__global__ __launch_bounds__(256) void node_gat_fused_k(
    const _Float16* __restrict__ xl16, const _Float16* __restrict__ xr16,
    const _Float16* __restrict__ eattB, const int* __restrict__ srcB,
    const int* __restrict__ offs,
    const float* __restrict__ We, const float* __restrict__ att,
    const float* __restrict__ bias, _Float16* __restrict__ hout) {
  __shared__ half8_t WeS[FEAT_E][16];  // WeS[f][q] = We[f][8q..8q+7], 4 KB
  const int tid = threadIdx.x;
  {
    const int f = tid >> 4, q = tid & 15;
    const float4 w0 = ((const float4*)We)[f * 32 + q * 2];
    const float4 w1 = ((const float4*)We)[f * 32 + q * 2 + 1];
    WeS[f][q] = (half8_t){(_Float16)w0.x, (_Float16)w0.y, (_Float16)w0.z, (_Float16)w0.w,
                          (_Float16)w1.x, (_Float16)w1.y, (_Float16)w1.z, (_Float16)w1.w};
  }
  __syncthreads();

  const int wave = tid >> 6, lane = tid & 63;
  const int slot = lane >> 4, l16 = lane & 15;
  const int d = blockIdx.x * 4 + wave;  // grid = NN/4 exactly

  const float4 af0 = ((const float4*)att)[l16 * 2];
  const float4 af1 = ((const float4*)att)[l16 * 2 + 1];
  const half2_t at01 = {(_Float16)af0.x, (_Float16)af0.y};
  const half2_t at23 = {(_Float16)af0.z, (_Float16)af0.w};
  const half2_t at45 = {(_Float16)af1.x, (_Float16)af1.y};
  const half2_t at67 = {(_Float16)af1.z, (_Float16)af1.w};

  const half8_t xrh = *(const half8_t*)(xr16 + (size_t)d * HIDD + l16 * 8);
  const int o0 = offs[d], o1 = offs[d + 1];

  float acc0 = 0.f, acc1 = 0.f, acc2 = 0.f, acc3 = 0.f;
  float acc4 = 0.f, acc5 = 0.f, acc6 = 0.f, acc7 = 0.f;
  float den = 0.f;

#define FINISH_EDGE(XL, EM, V)                                           \
  {                                                                      \
    half8_t m_ = ((XL) + xrh) + (EM);                                    \
    half8_t lk_ = hmax8(m_, m_ * splat8((_Float16)0.2f));                \
    float p_ = dot_att(lk_, at01, at23, at45, at67);                     \
    p_ += __shfl_xor(p_, 1);                                             \
    p_ += __shfl_xor(p_, 2);                                             \
    const float w_ = (V) ? __expf(p_) : 0.f;                             \
    den += w_;                                                           \
    acc0 = fmaf(w_, (float)(XL)[0], acc0);                               \
    acc1 = fmaf(w_, (float)(XL)[1], acc1);                               \
    acc2 = fmaf(w_, (float)(XL)[2], acc2);                               \
    acc3 = fmaf(w_, (float)(XL)[3], acc3);                               \
    acc4 = fmaf(w_, (float)(XL)[4], acc4);                               \
    acc5 = fmaf(w_, (float)(XL)[5], acc5);                               \
    acc6 = fmaf(w_, (float)(XL)[6], acc6);                               \
    acc7 = fmaf(w_, (float)(XL)[7], acc7);                               \
  }

  for (int j = o0 + slot * 2; j < o1; j += 8) {
    const bool v1 = (j + 1) < o1;
    const int j1 = v1 ? j + 1 : j;          // clamp keeps loads in-bounds
    const int s0 = srcB[j];
    const int s1 = srcB[j1];
    const half8_t x0 = *(const half8_t*)(xl16 + (unsigned)s0 * 128u + l16 * 8);
    const half8_t x1 = *(const half8_t*)(xl16 + (unsigned)s1 * 128u + l16 * 8);
    const half8_t a0 = *(const half8_t*)(eattB + (unsigned)j * 16u);
    const half8_t b0 = *(const half8_t*)(eattB + (unsigned)j * 16u + 8u);
    const half8_t a1 = *(const half8_t*)(eattB + (unsigned)j1 * 16u);
    const half8_t b1 = *(const half8_t*)(eattB + (unsigned)j1 * 16u + 8u);
    half8_t em0 = {}, em1 = {};
#pragma unroll
    for (int f = 0; f < 8; ++f) {
      const half8_t wf = WeS[f][l16];  // shared by the pair
      em0 += splat8(a0[f]) * wf;
      em1 += splat8(a1[f]) * wf;
    }
#pragma unroll
    for (int f = 0; f < 8; ++f) {
      const half8_t wf = WeS[8 + f][l16];
      em0 += splat8(b0[f]) * wf;
      em1 += splat8(b1[f]) * wf;
    }
    FINISH_EDGE(x0, em0, true)
    FINISH_EDGE(x1, em1, v1)
  }
#undef FINISH_EDGE

  // combine 4 slots
#define RED(A) A += __shfl_xor(A, 16); A += __shfl_xor(A, 32);
  RED(acc0) RED(acc1) RED(acc2) RED(acc3)
  RED(acc4) RED(acc5) RED(acc6) RED(acc7)
  RED(den)
#undef RED
  if (slot == 0) {
    const float inv = 1.f / (den + 1e-16f);
    const float4 b0 = ((const float4*)bias)[l16 * 2];
    const float4 b1 = ((const float4*)bias)[l16 * 2 + 1];
    float o0f = fmaf(acc0, inv, b0.x), o1f = fmaf(acc1, inv, b0.y);
    float o2f = fmaf(acc2, inv, b0.z), o3f = fmaf(acc3, inv, b0.w);
    float o4f = fmaf(acc4, inv, b1.x), o5f = fmaf(acc5, inv, b1.y);
    float o6f = fmaf(acc6, inv, b1.z), o7f = fmaf(acc7, inv, b1.w);
    o0f = o0f > 0.f ? o0f : expm1f(o0f);  o1f = o1f > 0.f ? o1f : expm1f(o1f);
    o2f = o2f > 0.f ? o2f : expm1f(o2f);  o3f = o3f > 0.f ? o3f : expm1f(o3f);
    o4f = o4f > 0.f ? o4f : expm1f(o4f);  o5f = o5f > 0.f ? o5f : expm1f(o5f);
    o6f = o6f > 0.f ? o6f : expm1f(o6f);  o7f = o7f > 0.f ? o7f : expm1f(o7f);
    half8_t ho = {(_Float16)o0f, (_Float16)o1f, (_Float16)o2f, (_Float16)o3f,
                  (_Float16)o4f, (_Float16)o5f, (_Float16)o6f, (_Float16)o7f};
    *(half8_t*)(hout + (size_t)d * HIDD + l16 * 8) = ho;
  }
}

// ---- graph pooling (fp16 h) ----
__global__ void pool_k(const _Float16* __restrict__ h, const int* __restrict__ batch,
                       float* __restrict__ gsum, unsigned int* __restrict__ gmax,
                       float* __restrict__ gcnt) {
  __shared__ float ssum[NGRAPH][HIDD];
  __shared__ float smax[NGRAPH][HIDD];
  __shared__ float scnt[NGRAPH];
  const int t = threadIdx.x;
#pragma unroll
  for (int g = 0; g < NGRAPH; ++g) {
    ssum[g][t] = 0.f;
    smax[g][t] = -3.0e38f;
  }
  if (t < NGRAPH) scnt[t] = 0.f;
  __syncthreads();
  const int n0 = blockIdx.x * 64;
  const int nEnd = (n0 + 64 < NN) ? (n0 + 64) : NN;
  unsigned int seen = 0;
  for (int n = n0; n < nEnd; ++n) {
    const int g = batch[n];
    seen |= 1u << g;
    const float v = (float)h[(size_t)n * HIDD + t];
    ssum[g][t] += v;
    smax[g][t] = fmaxf(smax[g][t], v);
    if (t == 0) scnt[g] += 1.f;
  }
  __syncthreads();
  for (int g = 0; g < NGRAPH; ++g) {
    if (seen & (1u << g)) {
      atomicAdd(&gsum[g * HIDD + t], ssum[g][t]);
      atomicMax(&gmax[g * HIDD + t], fenc(smax[g][t]));
      if (t == 0) atomicAdd(&gcnt[g], scnt[g]);
    }
  }
}

// ---- FC head ----
__global__ void head_k(const float* __restrict__ suma, const unsigned int* __restrict__ maxa,
                       const float* __restrict__ cnta,
                       const float* __restrict__ sumb, const unsigned int* __restrict__ maxb,
                       const float* __restrict__ cntb,
                       const float* __restrict__ Wf1, const float* __restrict__ bf1,
                       const float* __restrict__ Wf2, const float* __restrict__ bf2,
                       float* __restrict__ out) {
  __shared__ float c[4 * HIDD];
  __shared__ float red[HIDD];
  const int g = blockIdx.x, t = threadIdx.x;  // 128 threads
  const float ca = fmaxf(cnta[g], 1.f), cb = fmaxf(cntb[g], 1.f);
  c[t]            = suma[g * HIDD + t] / ca;
  c[HIDD + t]     = fdec(maxa[g * HIDD + t]);
  c[2 * HIDD + t] = sumb[g * HIDD + t] / cb;
  c[3 * HIDD + t] = fdec(maxb[g * HIDD + t]);
  __syncthreads();
  float acc = bf1[t];
  for (int i = 0; i < 4 * HIDD; ++i)
    acc = fmaf(c[i], Wf1[(size_t)i * HIDD + t], acc);
  acc = fmaxf(acc, 0.f);
  red[t] = acc * Wf2[t];
  __syncthreads();
  for (int s2 = 64; s2 > 0; s2 >>= 1) {
    if (t < s2) red[t] += red[t + s2];
    __syncthreads();
  }
  if (t == 0) out[g] = 1.f / (1.f + expf(-(red[0] + bf2[0])));
}

extern "C" void kernel_launch(void* const* d_in, const int* in_sizes, int n_in,
                              void* d_out, int out_size, void* d_ws, size_t ws_size,
                              hipStream_t stream) {
  (void)in_sizes; (void)n_in; (void)out_size; (void)ws_size;
  const float* xA    = (const float*)d_in[0];
  const int*   eiA   = (const int*)  d_in[1];
  const float* eaA   = (const float*)d_in[2];
  const int*   batA  = (const int*)  d_in[3];
  const float* xB    = (const float*)d_in[4];
  const int*   eiB   = (const int*)  d_in[5];
  const float* eaB   = (const float*)d_in[6];
  const int*   batB  = (const int*)  d_in[7];
  const float* W1l   = (const float*)d_in[8];
  const float* b1l   = (const float*)d_in[9];
  const float* W1r   = (const float*)d_in[10];
  const float* b1r   = (const float*)d_in[11];
  const float* W1e   = (const float*)d_in[12];
  const float* att1  = (const float*)d_in[13];
  const float* bias1 = (const float*)d_in[14];
  const float* W2l   = (const float*)d_in[15];
  const float* b2l   = (const float*)d_in[16];
  const float* W2r   = (const float*)d_in[17];
  const float* b2r   = (const float*)d_in[18];
  const float* W2e   = (const float*)d_in[19];
  const float* att2  = (const float*)d_in[20];
  const float* bias2 = (const float*)d_in[21];
  const float* Wf1   = (const float*)d_in[22];
  const float* bf1   = (const float*)d_in[23];
  const float* Wf2   = (const float*)d_in[24];
  const float* bf2   = (const float*)d_in[25];

  char* ws = (char*)d_ws;
  size_t off = 0;
  auto alloc = [&](size_t bytes) -> void* {
    void* p = ws + off;
    off += (bytes + 255) & ~(size_t)255;
    return p;
  };
  _Float16* h16    = (_Float16*)alloc((size_t)NN * HIDD * 2);
  _Float16* xl16   = (_Float16*)alloc((size_t)NN * HIDD * 2);
  _Float16* xr16   = (_Float16*)alloc((size_t)NN * HIDD * 2);
  int*      srcB   = (int*)     alloc((size_t)NE * 4);
  _Float16* eattB  = (_Float16*)alloc((size_t)NE * FEAT_E * 2);
  int*      cnt    = (int*)     alloc((size_t)NN * 4);
  int*      offs   = (int*)     alloc((size_t)(NN + 1) * 4);
  int*      cursor = (int*)     alloc((size_t)NN * 4);
  _Float16* wtg1   = (_Float16*)alloc(2 * 128 * 128 * 2);
  _Float16* wtg2   = (_Float16*)alloc(2 * 128 * 128 * 2);
  const size_t poolStart = off;
  float*        psumA = (float*)alloc(NGRAPH * HIDD * 4);
  unsigned int* pmaxA = (unsigned int*)alloc(NGRAPH * HIDD * 4);
  float*        pcntA = (float*)alloc(NGRAPH * 4);
  float*        psumB = (float*)alloc(NGRAPH * HIDD * 4);
  unsigned int* pmaxB = (unsigned int*)alloc(NGRAPH * HIDD * 4);
  float*        pcntB = (float*)alloc(NGRAPH * 4);
  const size_t poolBytes = off - poolStart;

  const float* xs[2]   = {xA, xB};
  const int*   eis[2]  = {eiA, eiB};
  const float* eas[2]  = {eaA, eaB};
  const int*   bats[2] = {batA, batB};
  float*        psums[2] = {psumA, psumB};
  unsigned int* pmaxs[2] = {pmaxA, pmaxB};
  float*        pcnts[2] = {pcntA, pcntB};

  hipMemsetAsync(psumA, 0, poolBytes, stream);  // 0 == encoded -inf for max
  prep_wt_k<<<256, 128, 0, stream>>>(W1l, W1r, wtg1);
  prep_wt_k<<<256, 128, 0, stream>>>(W2l, W2r, wtg2);

  for (int g = 0; g < 2; ++g) {
    const int* src = eis[g];
    const int* dst = eis[g] + NE;
    // dense in-edge CSR: count -> scan -> place (dst-sorted src + edge attrs)
    hipMemsetAsync(cnt, 0, (size_t)NN * 4, stream);
    count_k<<<NE / 256, 256, 0, stream>>>(dst, cnt);
    scan_k<<<1, 1024, 0, stream>>>(cnt, offs, cursor);
    place_k<<<NE / 256, 256, 0, stream>>>(src, dst, eas[g], cursor, srcB, eattB);
    // layer 1 (fp32 x input)
    node_linear_mfma_k<float><<<dim3((NN + 63) / 64, 2), 256, 0, stream>>>(
        xs[g], wtg1, b1l, b1r, xl16, xr16);
    node_gat_fused_k<<<NN / 4, 256, 0, stream>>>(xl16, xr16, eattB, srcB, offs,
                                                 W1e, att1, bias1, h16);
    // layer 2 (fp16 h input)
    node_linear_mfma_k<_Float16><<<dim3((NN + 63) / 64, 2), 256, 0, stream>>>(
        h16, wtg2, b2l, b2r, xl16, xr16);
    node_gat_fused_k<<<NN / 4, 256, 0, stream>>>(xl16, xr16, eattB, srcB, offs,
                                                 W2e, att2, bias2, h16);
    // pooling
    pool_k<<<(NN + 63) / 64, 128, 0, stream>>>(h16, bats[g], psums[g], pmaxs[g], pcnts[g]);
  }
  head_k<<<NGRAPH, 128, 0, stream>>>(psumA, pmaxA, pcntA, psumB, pmaxB, pcntB,
                                     Wf1, bf1, Wf2, bf2, (float*)d_out);
}